// Round 28
// baseline (309.028 us; speedup 1.0000x reference)
//
#include <hip/hip_runtime.h>
#include <math.h>

#define S_ 4
#define L_ 2048
#define D_ 1024
#define H_ 16
#define DH_ 64
#define TTOT_ 8192
#define WCL_ 384
#define KMAX_ 16
#define MAXCL_ (S_*KMAX_)
#define MAXLEN_ (WCL_+1)   // 385
#define LSCAP_ 4096
#define NELEM_ ((size_t)TTOT_*(size_t)D_)

typedef __attribute__((ext_vector_type(8))) short bf16x8;
typedef __attribute__((ext_vector_type(4))) float f32x4;
typedef __attribute__((ext_vector_type(4))) unsigned short u16x4;

// bf16 helpers (RNE)
__device__ __forceinline__ unsigned short bfh(float x) {
  unsigned u = __float_as_uint(x);
  return (unsigned short)((u + 0x7FFFu + ((u >> 16) & 1u)) >> 16);
}
__device__ __forceinline__ float bff(unsigned short h) {
  return __uint_as_float(((unsigned)h) << 16);
}
__device__ __forceinline__ unsigned pk2(unsigned short a, unsigned short b) {
  return (unsigned)a | ((unsigned)b << 16);
}
// XOR swizzle on ushort index within [row][64] tiles (16B-chunk granularity)
#define SWZ(r, c) (((r) << 6) + ((c) ^ (((r) & 7) << 3)))

__device__ __forceinline__ void glds16(const void* g, void* l) {
  __builtin_amdgcn_global_load_lds(
      (const __attribute__((address_space(1))) unsigned int*)g,
      (__attribute__((address_space(3))) unsigned int*)l, 16, 0, 0);
}

#define N4W_ ((1 << 20) / 4)
#define N4IN_ ((int)(NELEM_ / 4))
#define NWM_ (64 * 1024)

// ---------------------------------------------------------------------------
// Fused Wm[d][k] = (1/16) sum_h W[h*64+d][k] for both Wq and Wk (grid.y)
// (exact f32 routing path — must run before feats)
// ---------------------------------------------------------------------------
__global__ __launch_bounds__(256)
void wmean2(const float* __restrict__ Wq, const float* __restrict__ Wk,
            float* __restrict__ Wqm, float* __restrict__ Wkm) {
  const float* __restrict__ W = blockIdx.y ? Wk : Wq;
  float* __restrict__ Wm = blockIdx.y ? Wkm : Wqm;
  int i = blockIdx.x * 256 + threadIdx.x;
  if (i >= NWM_) return;
  int d = i >> 10, kk = i & 1023;
  float s = 0.f;
#pragma unroll
  for (int h = 0; h < 16; h++) s += W[(size_t)(h * 64 + d) * 1024 + kk];
  Wm[i] = s * (1.0f / 16.0f);
}

// ---------------------------------------------------------------------------
// Fused feats GEMM + conversions: blocks 0..255 = exact gemm_feats body
// (C[M,64] = A[M,1024]*B[64,1024]^T, exact f32); blocks 256+ = Wq/Wk/Wv/Wo hi
// + q/k/v hi conversions (exact conv bodies).
// ---------------------------------------------------------------------------
__global__ __launch_bounds__(256)
void feats_conv(const float* __restrict__ q_in, const float* __restrict__ k_in,
                const float* __restrict__ v_in,
                const float* __restrict__ Wqm, const float* __restrict__ Wkm,
                float* __restrict__ FQ, float* __restrict__ FK,
                const float* __restrict__ Wq, const float* __restrict__ Wk,
                const float* __restrict__ Wv, const float* __restrict__ Wo,
                unsigned short* __restrict__ WqH, unsigned short* __restrict__ WkH,
                unsigned short* __restrict__ WvH, unsigned short* __restrict__ WoH,
                unsigned short* __restrict__ QSh, unsigned short* __restrict__ KSh,
                unsigned short* __restrict__ VSh) {
  if (blockIdx.x < 256) {
    // ---- feats GEMM (exact f32; identical to gemm_feats) ----
    const int by = blockIdx.x >> 7;              // 0: q, 1: k
    const float* __restrict__ A = by ? k_in : q_in;
    const float* __restrict__ B = by ? Wkm : Wqm;
    float* __restrict__ C = by ? FK : FQ;
    const int Kd = 1024, N = 64;
    __shared__ float As[16][68];
    __shared__ float Bs[16][68];
    const int tx = threadIdx.x & 15, ty = threadIdx.x >> 4;
    const int m0 = (blockIdx.x & 127) * 64;
    const int lr = threadIdx.x >> 2, lc = threadIdx.x & 3;
    float acc[4][4] = {};
    for (int k0 = 0; k0 < Kd; k0 += 16) {
      __syncthreads();
      float4 a4 = *(const float4*)(A + (size_t)(m0 + lr) * Kd + k0 + lc * 4);
      float4 b4 = *(const float4*)(B + (size_t)lr * Kd + k0 + lc * 4);
      As[lc*4+0][lr] = a4.x; As[lc*4+1][lr] = a4.y; As[lc*4+2][lr] = a4.z; As[lc*4+3][lr] = a4.w;
      Bs[lc*4+0][lr] = b4.x; Bs[lc*4+1][lr] = b4.y; Bs[lc*4+2][lr] = b4.z; Bs[lc*4+3][lr] = b4.w;
      __syncthreads();
#pragma unroll
      for (int kk = 0; kk < 16; kk++) {
        float4 av = *(const float4*)&As[kk][ty * 4];
        float4 bv = *(const float4*)&Bs[kk][tx * 4];
        float aa[4] = {av.x, av.y, av.z, av.w};
        float bb[4] = {bv.x, bv.y, bv.z, bv.w};
#pragma unroll
        for (int i = 0; i < 4; i++)
#pragma unroll
          for (int j = 0; j < 4; j++) acc[i][j] += aa[i] * bb[j];
      }
    }
#pragma unroll
    for (int i = 0; i < 4; i++)
#pragma unroll
      for (int j = 0; j < 4; j++)
        C[(size_t)(m0 + ty * 4 + i) * N + (tx * 4 + j)] = acc[i][j];
    return;
  }
  // ---- conversion blocks ----
  int i = (blockIdx.x - 256) * 256 + threadIdx.x;
  if (i < 4 * N4W_) {
    int w = i / N4W_, j = i % N4W_;
    const float* src = (w == 0) ? Wq : (w == 1) ? Wk : (w == 2) ? Wv : Wo;
    unsigned short* dst = (w == 0) ? WqH : (w == 1) ? WkH : (w == 2) ? WvH : WoH;
    float4 v = ((const float4*)src)[j];
    *(uint2*)&dst[(size_t)j * 4] =
        make_uint2(pk2(bfh(v.x), bfh(v.y)), pk2(bfh(v.z), bfh(v.w)));
    return;
  }
  i -= 4 * N4W_;
  if (i >= 3 * N4IN_) return;
  int w = i / N4IN_, j = i % N4IN_;
  const float* src = (w == 0) ? q_in : (w == 1) ? k_in : v_in;
  unsigned short* dh = (w == 0) ? QSh : (w == 1) ? KSh : VSh;
  float4 v = ((const float4*)src)[j];
  *(uint2*)&dh[(size_t)j * 4] =
      make_uint2(pk2(bfh(v.x), bfh(v.y)), pk2(bfh(v.z), bfh(v.w)));
}

// ---------------------------------------------------------------------------
// 1-term bf16 GEMM core (a_hi * W_hi), hi-only bf16 C. 32 KB LDS; 256 thr.
// M = TTOT_, N = Kd = D_. Requires block index b in [0, 512).
// ---------------------------------------------------------------------------
__device__ __forceinline__
void gemm1_body(const unsigned short* __restrict__ Ah,
                const unsigned short* __restrict__ Bh,
                unsigned short* __restrict__ Ch,
                int b, unsigned char* smem) {
  const int Kd = D_, N = D_;
  const int m0 = (b & 63) * 128, n0 = (b >> 6) * 128;
  unsigned short* LA = (unsigned short*)smem;    // 16 KB
  unsigned short* LB = LA + 8192;                // 16 KB
  const int tid = threadIdx.x, wave = tid >> 6, lane = tid & 63;
  const int lm = lane & 15, lg = lane >> 4;
  const int wr = wave >> 1, wc = wave & 1;
  const int lrow = lane >> 3;
  const int lchk = (lane & 7) ^ lrow;
  f32x4 acc[4][4];
#pragma unroll
  for (int i = 0; i < 4; i++)
#pragma unroll
    for (int j = 0; j < 4; j++) acc[i][j] = (f32x4){0.f, 0.f, 0.f, 0.f};
  for (int k0 = 0; k0 < Kd; k0 += 64) {
    __syncthreads();
#pragma unroll
    for (int i = 0; i < 4; i++) {
      const int r = wave * 32 + i * 8;
      const size_t ga = (size_t)(m0 + r + lrow) * Kd + k0 + lchk * 8;
      const size_t gb = (size_t)(n0 + r + lrow) * Kd + k0 + lchk * 8;
      glds16(&Ah[ga], &LA[r * 64]);
      glds16(&Bh[gb], &LB[r * 64]);
    }
    __syncthreads();
#pragma unroll
    for (int s = 0; s < 2; s++) {
      bf16x8 ah[4], bh[4];
#pragma unroll
      for (int i = 0; i < 4; i++) {
        const int ra = wr * 64 + i * 16 + lm;
        const int ca = ((s * 4 + lg) ^ (ra & 7)) * 8;
        ah[i] = *(const bf16x8*)&LA[ra * 64 + ca];
        const int rb = wc * 64 + i * 16 + lm;
        const int cb = ((s * 4 + lg) ^ (rb & 7)) * 8;
        bh[i] = *(const bf16x8*)&LB[rb * 64 + cb];
      }
#pragma unroll
      for (int i = 0; i < 4; i++)
#pragma unroll
        for (int j = 0; j < 4; j++)
          acc[i][j] = __builtin_amdgcn_mfma_f32_16x16x32_bf16(ah[i], bh[j], acc[i][j], 0, 0, 0);
    }
  }
#pragma unroll
  for (int i = 0; i < 4; i++)
#pragma unroll
    for (int j = 0; j < 4; j++) {
      const int rowb = m0 + wr * 64 + i * 16 + lg * 4;
      const int col = n0 + wc * 64 + j * 16 + lm;
#pragma unroll
      for (int r = 0; r < 4; r++)
        Ch[(size_t)(rowb + r) * N + col] = bfh(acc[i][j][r]);
    }
}

// ---------------------------------------------------------------------------
// Wo GEMM with fused normalize: A = bfh(OH[row]*1/max(cnt,1)) staged via
// registers + ds_write (bit-identical to norm_h + gemm_o1). GRID = 512.
// ---------------------------------------------------------------------------
__global__ __launch_bounds__(256)
void gemm_on(const float* __restrict__ OHf, const int* __restrict__ cnt,
             const unsigned short* __restrict__ Bh,
             float* __restrict__ C) {
  __shared__ __align__(16) unsigned short LA[128 * 64];
  __shared__ __align__(16) unsigned short LB[128 * 64];
  const int Kd = D_, N = D_;
  const int tid = threadIdx.x, wave = tid >> 6, lane = tid & 63;
  const int lm = lane & 15, lg = lane >> 4;
  const int m0 = (blockIdx.x & 63) * 128, n0 = (blockIdx.x >> 6) * 128;
  const int wr = wave >> 1, wc = wave & 1;
  const int lrow = lane >> 3;
  const int lchk = (lane & 7) ^ lrow;
  f32x4 acc[4][4];
#pragma unroll
  for (int i = 0; i < 4; i++)
#pragma unroll
    for (int j = 0; j < 4; j++) acc[i][j] = (f32x4){0.f, 0.f, 0.f, 0.f};
  for (int k0 = 0; k0 < Kd; k0 += 64) {
    __syncthreads();
#pragma unroll
    for (int i = 0; i < 4; i++) {
      const int r = wave * 32 + i * 8;
      const int arow = m0 + r + lrow;
      const float* asrc = OHf + (size_t)arow * Kd + k0 + lchk * 8;
      float4 a0 = *(const float4*)asrc;
      float4 a1 = *(const float4*)(asrc + 4);
      int cc = cnt[arow];
      float sc = 1.0f / (float)(cc > 1 ? cc : 1);
      uint4 pk;
      pk.x = pk2(bfh(a0.x * sc), bfh(a0.y * sc));
      pk.y = pk2(bfh(a0.z * sc), bfh(a0.w * sc));
      pk.z = pk2(bfh(a1.x * sc), bfh(a1.y * sc));
      pk.w = pk2(bfh(a1.z * sc), bfh(a1.w * sc));
      *(uint4*)&LA[r * 64 + lane * 8] = pk;
      const size_t gb = (size_t)(n0 + r + lrow) * Kd + k0 + lchk * 8;
      glds16(&Bh[gb], &LB[r * 64]);
    }
    __syncthreads();
#pragma unroll
    for (int s = 0; s < 2; s++) {
      bf16x8 ah[4], bh[4];
#pragma unroll
      for (int i = 0; i < 4; i++) {
        const int ra = wr * 64 + i * 16 + lm;
        const int ca = ((s * 4 + lg) ^ (ra & 7)) * 8;
        ah[i] = *(const bf16x8*)&LA[ra * 64 + ca];
        const int rb = wc * 64 + i * 16 + lm;
        const int cb = ((s * 4 + lg) ^ (rb & 7)) * 8;
        bh[i] = *(const bf16x8*)&LB[rb * 64 + cb];
      }
#pragma unroll
      for (int i = 0; i < 4; i++)
#pragma unroll
        for (int j = 0; j < 4; j++)
          acc[i][j] = __builtin_amdgcn_mfma_f32_16x16x32_bf16(ah[i], bh[j], acc[i][j], 0, 0, 0);
    }
  }
#pragma unroll
  for (int i = 0; i < 4; i++)
#pragma unroll
    for (int j = 0; j < 4; j++) {
      const int rowb = m0 + wr * 64 + i * 16 + lg * 4;
      const int col = n0 + wc * 64 + j * 16 + lm;
#pragma unroll
      for (int r = 0; r < 4; r++)
        C[(size_t)(rowb + r) * N + col] = acc[i][j][r];
    }
}

// ---------------------------------------------------------------------------
// FE[t] = 0.5*(l2n(FQ[t]) + l2n(FK[t]))   (one wave per token; unchanged)
// ---------------------------------------------------------------------------
__global__ __launch_bounds__(256)
void l2comb(const float* __restrict__ FQ, const float* __restrict__ FK,
            float* __restrict__ FE) {
  int t = blockIdx.x * 4 + (threadIdx.x >> 6);
  int lane = threadIdx.x & 63;
  if (t >= TTOT_) return;
  float q = FQ[(size_t)t * 64 + lane], k = FK[(size_t)t * 64 + lane];
  float q2 = q * q, k2 = k * k;
#pragma unroll
  for (int m = 1; m < 64; m <<= 1) {
    q2 += __shfl_xor(q2, m, 64);
    k2 += __shfl_xor(k2, m, 64);
  }
  FE[(size_t)t * 64 + lane] =
      0.5f * (q / (sqrtf(q2) + 1e-6f) + k / (sqrtf(k2) + 1e-6f));
}

// ---------------------------------------------------------------------------
// Routing body, 1024 threads — EXACT R10/R13 numerics. R28: assignment passes
// restructured c4-outer with sd[KMAX] register accumulators (j fully unrolled
// with j<k guard -> static indices -> registers; kills the fr[16]=64-VGPR
// scratch spill at the 64-VGPR budget). Per-(token,j) FP add chain is
// c4-ascending, x,y,z,w within — identical order -> bit-identical.
// Keeps R26 LDS-chunked centroid + R24 wave-sync bitonic + setprio.
// ---------------------------------------------------------------------------
__device__ void routing_body(int s, const float* __restrict__ FE,
                             const int* __restrict__ seqlens,
                             const int* __restrict__ gidx, int* __restrict__ cT,
                             int* __restrict__ cL, int* __restrict__ tC,
                             unsigned char* smem) {
  __builtin_amdgcn_s_setprio(1);   // routing is the latency-critical path
  unsigned long long* keys = (unsigned long long*)smem;        // 32 KB
  unsigned char* assign = smem + 32768;                        // 4 KB
  float (*cent)[64] = (float(*)[64])(smem + 36864);            // 4 KB
  int* cnt1 = (int*)(smem + 40960);
  int* cnt2 = cnt1 + KMAX_;
  int* starts = cnt2 + KMAX_;
  float* fstage = (float*)smem;    // aliases keys: dead during centroid phase

  const int tid = threadIdx.x;
  int a = 0;
  for (int t = 0; t < s; t++) a += seqlens[t];
  int Ls = seqlens[s];
  if (Ls > LSCAP_) Ls = LSCAP_;
  for (int cs = tid; cs < KMAX_; cs += 1024) cL[s * KMAX_ + cs] = 0;
  if (Ls <= 0) return;

  int wloc = Ls < WCL_ ? Ls : WCL_;
  if (wloc < 1) wloc = 1;
  int k = (Ls + wloc - 1) / wloc;
  if (k < 1) k = 1;
  if (k > KMAX_) k = KMAX_;

  if (tid < k * 64) {
    int j = tid >> 6, d = tid & 63;
    double step = (k > 1) ? (double)(Ls - 1) / (double)(k - 1) : 0.0;
    long ii = (long)rint(step * (double)j);
    if (ii < 0) ii = 0;
    if (ii > Ls - 1) ii = Ls - 1;
    cent[j][d] = FE[(size_t)(a + ii) * DH_ + d];
  }
  if (tid < KMAX_) { cnt1[tid] = 0; cnt2[tid] = 0; }
  __syncthreads();

  // ---- assignment pass 1 (c4-outer, sd[j] register accumulators) ----
  for (int base2 = 0; base2 < Ls; base2 += 1024) {
    int i = base2 + tid;
    int aj = -1;
    if (i < Ls) {
      const float4* f4 = (const float4*)(FE + (size_t)(a + i) * DH_);
      float sd[KMAX_];
#pragma unroll
      for (int j = 0; j < KMAX_; j++) sd[j] = 0.f;
      for (int c4 = 0; c4 < 16; c4++) {
        float4 fr = f4[c4];
#pragma unroll
        for (int j = 0; j < KMAX_; j++) {
          if (j < k) {
            float4 cv = *(const float4*)&cent[j][c4 * 4];
            sd[j] += fr.x * cv.x; sd[j] += fr.y * cv.y;
            sd[j] += fr.z * cv.z; sd[j] += fr.w * cv.w;
          }
        }
      }
      float best = -1e30f; int bj = 0;
#pragma unroll
      for (int j = 0; j < KMAX_; j++) {
        if (j < k && sd[j] > best) { best = sd[j]; bj = j; }
      }
      assign[i] = (unsigned char)bj;
      aj = bj;
    }
    for (int j = 0; j < k; j++) {
      unsigned long long m = __ballot(aj == j);
      if ((tid & 63) == 0 && m) atomicAdd(&cnt1[j], (int)__popcll(m));
    }
  }
  __syncthreads();

  // ---- exact np.add.at centroid accumulation, LDS-chunked (128 rows/chunk).
  float csum_acc = 0.f;
  const int jj = tid >> 6, dd = tid & 63;
  for (int base = 0; base < Ls; base += 128) {
    const int cr = (Ls - base < 128) ? (Ls - base) : 128;
    __syncthreads();   // accumulators done with previous chunk
#pragma unroll
    for (int f = tid; f < 128 * 16; f += 1024) {
      int row = f >> 4;
      if (row < cr)
        ((float4*)fstage)[f] =
            *(const float4*)(FE + (size_t)(a + base + row) * DH_ + (f & 15) * 4);
    }
    __syncthreads();   // chunk staged
    if (jj < k) {
      const float* fp = fstage + dd;
      int i = 0;
      for (; i + 16 <= cr; i += 16) {
        float v[16];
#pragma unroll
        for (int u = 0; u < 16; u++) v[u] = fp[(i + u) * DH_];
        unsigned char aa[16];
#pragma unroll
        for (int u = 0; u < 16; u++) aa[u] = assign[base + i + u];
#pragma unroll
        for (int u = 0; u < 16; u++)
          csum_acc += (aa[u] == (unsigned char)jj) ? v[u] : 0.0f;
      }
      for (; i < cr; i++)
        csum_acc += (assign[base + i] == (unsigned char)jj) ? fp[i * DH_] : 0.0f;
    }
  }
  __syncthreads();
  if (tid < k * 64) {
    float v = csum_acc / fmaxf((float)cnt1[jj], 1.0f);
    float sq = v * v;
#pragma unroll
    for (int m = 1; m < 64; m <<= 1) sq += __shfl_xor(sq, m, 64);
    cent[jj][dd] = v / (sqrtf(sq) + 1e-6f);
  }
  __syncthreads();

  // ---- assignment pass 2 + sort keys (c4-outer, sd[j] registers) ----
  int NP2 = 1;
  while (NP2 < Ls) NP2 <<= 1;
  for (int base2 = 0; base2 < NP2; base2 += 1024) {
    int i = base2 + tid;
    int aj = -1;
    if (i < NP2) {
      unsigned long long key;
      if (i < Ls) {
        const float4* f4 = (const float4*)(FE + (size_t)(a + i) * DH_);
        float sd[KMAX_];
#pragma unroll
        for (int j = 0; j < KMAX_; j++) sd[j] = 0.f;
        for (int c4 = 0; c4 < 16; c4++) {
          float4 fr = f4[c4];
#pragma unroll
          for (int j = 0; j < KMAX_; j++) {
            if (j < k) {
              float4 cv = *(const float4*)&cent[j][c4 * 4];
              sd[j] += fr.x * cv.x; sd[j] += fr.y * cv.y;
              sd[j] += fr.z * cv.z; sd[j] += fr.w * cv.w;
            }
          }
        }
        float best = -1e30f; int bj = 0;
#pragma unroll
        for (int j = 0; j < KMAX_; j++) {
          if (j < k && sd[j] > best) { best = sd[j]; bj = j; }
        }
        aj = bj;
        unsigned int u = __float_as_uint(best);
        unsigned int ord = (u & 0x80000000u) ? ~u : (u | 0x80000000u);
        unsigned int dsc = ~ord;
        key = ((unsigned long long)bj << 45) |
              ((unsigned long long)dsc << 13) | (unsigned long long)i;
      } else {
        key = ~0ull;
      }
      keys[i] = key;
    }
    for (int j = 0; j < k; j++) {
      unsigned long long m = __ballot(aj == j);
      if ((tid & 63) == 0 && m) atomicAdd(&cnt2[j], (int)__popcll(m));
    }
  }
  __syncthreads();

  // ---- bitonic sort: full barrier only when partners cross waves (st>=64);
  // intra-wave stages rely on per-wave in-order DS + lgkmcnt(0). ----
  for (int len2 = 2; len2 <= NP2; len2 <<= 1) {
    for (int st = len2 >> 1; st > 0; st >>= 1) {
      if (st >= 64) {
        __syncthreads();
      } else {
        asm volatile("s_waitcnt lgkmcnt(0)" ::: "memory");
      }
      for (int i = tid; i < NP2; i += 1024) {
        int j = i ^ st;
        if (j > i) {
          unsigned long long x = keys[i], y = keys[j];
          bool asc = ((i & len2) == 0);
          if ((x > y) == asc) { keys[i] = y; keys[j] = x; }
        }
      }
    }
  }
  __syncthreads();
  if (tid == 0) {
    starts[0] = 0;
    for (int j = 0; j < k; j++) starts[j + 1] = starts[j] + cnt2[j];
  }
  __syncthreads();

  const int g = gidx[s];
  int cOut = 0;
  for (int j = 0; j < k; j++) {
    int cj = cnt2[j];
    if (cj <= 0) continue;
    int keep = cj < wloc ? cj : wloc;
    int slot = s * KMAX_ + cOut;
    for (int p = tid; p < keep; p += 1024) {
      int token = a + (int)(keys[starts[j] + p] & 0x1FFFull);
      cT[slot * MAXLEN_ + p] = token;
      atomicAdd(&tC[token], 1);
    }
    if (tid == 0) {
      cT[slot * MAXLEN_ + keep] = g;
      atomicAdd(&tC[g], 1);
      cL[slot] = keep + 1;
    }
    cOut++;
  }
}

// ---------------------------------------------------------------------------
// Mega-fused: blocks 0..3 routing @1024 thr; 4..515 Q-GEMM; 516..1027 K-GEMM;
// 1028..1539 V-GEMM (1-term, threads>=256 drop); 1540..3587 OH-zeroing.
// ---------------------------------------------------------------------------
__global__ __launch_bounds__(1024)
void fused_qkvr(const unsigned short* __restrict__ QAh,
                const unsigned short* __restrict__ WqH,
                unsigned short* __restrict__ Qh,
                const unsigned short* __restrict__ KAh,
                const unsigned short* __restrict__ WkH,
                unsigned short* __restrict__ Kh,
                const unsigned short* __restrict__ VAh,
                const unsigned short* __restrict__ WvH,
                unsigned short* __restrict__ Vh,
                float* __restrict__ OHz,
                const float* __restrict__ FE, const int* __restrict__ seqlens,
                const int* __restrict__ gidx, int* __restrict__ cT,
                int* __restrict__ cL, int* __restrict__ tC) {
  __shared__ __align__(16) unsigned char smem[49152];
  if (blockIdx.x < 4) {
    routing_body(blockIdx.x, FE, seqlens, gidx, cT, cL, tC, smem);
    return;
  }
  int b = blockIdx.x - 4;
  if (b >= 1536) {
    // OH zeroing: 2048 blocks x 1024 threads x 16B = 32 MB
    size_t o = (size_t)(b - 1536) * 1024 + threadIdx.x;
    ((float4*)OHz)[o] = (float4){0.f, 0.f, 0.f, 0.f};
    return;
  }
  if (threadIdx.x >= 256) return;     // free 12 of 16 waves
  if (b < 512) {
    gemm1_body(QAh, WqH, Qh, b, smem);
  } else if (b < 1024) {
    gemm1_body(KAh, WkH, Kh, b - 512, smem);
  } else {
    gemm1_body(VAh, WvH, Vh, b - 1024, smem);
  }
}

// ---------------------------------------------------------------------------
// MFMA flash attention v7 (unchanged): Q/K/V hi-only (QK: qh*kh; PV: ph*vh).
// XCD-grouped 1D grid, async reg-staged K/V, setprio, P bf16.
// LDS: toks 1.5K + QP 8K + KT 8K + VT 8K = 25.5 KB.
// ---------------------------------------------------------------------------
__global__ __launch_bounds__(256)
void attn_kernel(const unsigned short* __restrict__ Qh,
                 const unsigned short* __restrict__ Kh,
                 const unsigned short* __restrict__ Vh,
                 const int* __restrict__ cT, const int* __restrict__ cL,
                 float* __restrict__ OH) {
  const int flat = blockIdx.x;
  const int xcd = flat & 7;
  const int i8 = flat >> 3;              // 0..895
  const int qc = i8 % 7;
  const int g = xcd + 8 * (i8 / 7);      // 0..1023, g%8==xcd
  const int h = g & 15, c = g >> 4;

  const int len = cL[c];
  const int q0 = qc * 64;
  if (len <= 0 || q0 >= len) return;

  __shared__ int toks[MAXLEN_];
  __shared__ __align__(16) unsigned short QP[4096];  // Q hi tile -> P hi
  __shared__ __align__(16) unsigned short KT[4096];  // K hi
  __shared__ __align__(16) unsigned short VT[4096];  // V^T hi

  const int tid = threadIdx.x, wave = tid >> 6, lane = tid & 63;
  const int lm = lane & 15, lg = lane >> 4;
  const int lr8 = lane >> 3;            // row within 8-row slab (Q glds)
  const int lc8 = (lane & 7) ^ lr8;     // pre-swizzled source chunk (Q glds)

  const int krow = tid >> 2;
  const int kc = (tid & 3) * 16;
  const int dg = tid & 15, kg = tid >> 4;
  const int vd0 = dg * 4;

  for (int i = tid; i < len; i += 256) toks[i] = cT[c * MAXLEN_ + i];
  __syncthreads();

  uint4 ka0, ka1;
  u16x4 va0, va1, va2, va3;

#define KV_LOAD(mt_) do {                                                      \
    int kr_ = (mt_) * 64 + krow;                                               \
    int tk_ = toks[kr_ < len ? kr_ : 0];                                       \
    const unsigned short* kph = Kh + (size_t)tk_ * D_ + h * DH_ + kc;          \
    ka0 = *(const uint4*)(kph);  ka1 = *(const uint4*)(kph + 8);               \
    int vr_ = (mt_) * 64 + kg * 4;                                             \
    int t0_ = toks[vr_ + 0 < len ? vr_ + 0 : 0];                               \
    int t1_ = toks[vr_ + 1 < len ? vr_ + 1 : 0];                               \
    int t2_ = toks[vr_ + 2 < len ? vr_ + 2 : 0];                               \
    int t3_ = toks[vr_ + 3 < len ? vr_ + 3 : 0];                               \
    size_t off_ = (size_t)h * DH_ + vd0;                                       \
    va0 = *(const u16x4*)(Vh + (size_t)t0_ * D_ + off_);                       \
    va1 = *(const u16x4*)(Vh + (size_t)t1_ * D_ + off_);                       \
    va2 = *(const u16x4*)(Vh + (size_t)t2_ * D_ + off_);                       \
    va3 = *(const u16x4*)(Vh + (size_t)t3_ * D_ + off_);                       \
  } while (0)

#define KV_WRITE() do {                                                        \
    *(uint4*)&KT[SWZ(krow, kc)] = ka0;                                         \
    *(uint4*)&KT[SWZ(krow, kc + 8)] = ka1;                                     \
    _Pragma("unroll") for (int dd = 0; dd < 4; dd++) {                         \
      *(uint2*)&VT[SWZ(vd0 + dd, kg * 4)] =                                    \
          make_uint2(pk2(va0[dd], va1[dd]), pk2(va2[dd], va3[dd]));            \
    }                                                                          \
  } while (0)

  // ---- stage Q tile once (glds, source-swizzled, hi-only) ----
#pragma unroll
  for (int i = 0; i < 2; i++) {
    int slab = wave * 2 + i;                     // 0..7
    int r8 = slab * 8;
    int row = q0 + r8 + lr8;
    int tok = toks[row < len ? row : 0];
    glds16(Qh + (size_t)tok * D_ + h * DH_ + lc8 * 8, &QP[r8 * 64]);
  }
  KV_LOAD(0);
  __syncthreads();

  bf16x8 qAh[2];
#pragma unroll
  for (int s = 0; s < 2; s++)
    qAh[s] = *(const bf16x8*)&QP[SWZ(wave * 16 + lm, s * 32 + lg * 8)];

  f32x4 accO[4];
#pragma unroll
  for (int t = 0; t < 4; t++) accO[t] = (f32x4){0.f, 0.f, 0.f, 0.f};
  float mm[4] = {-INFINITY, -INFINITY, -INFINITY, -INFINITY};
  float ll[4] = {0.f, 0.f, 0.f, 0.f};

  const int ntile = (len + 63) >> 6;
  for (int mt = 0; mt < ntile; mt++) {
    __syncthreads();
    KV_WRITE();
    __syncthreads();
    if (mt + 1 < ntile) KV_LOAD(mt + 1);

    f32x4 sA[4];
#pragma unroll
    for (int t = 0; t < 4; t++) sA[t] = (f32x4){0.f, 0.f, 0.f, 0.f};
    __builtin_amdgcn_s_setprio(1);
#pragma unroll
    for (int t = 0; t < 4; t++) {
#pragma unroll
      for (int s = 0; s < 2; s++) {
        bf16x8 kb = *(const bf16x8*)&KT[SWZ(t * 16 + lm, s * 32 + lg * 8)];
        sA[t] = __builtin_amdgcn_mfma_f32_16x16x32_bf16(qAh[s], kb, sA[t], 0, 0, 0);
      }
    }
    __builtin_amdgcn_s_setprio(0);

    float sc[4][4];
#pragma unroll
    for (int t = 0; t < 4; t++) {
      bool kvalid = (mt * 64 + t * 16 + lm) < len;
#pragma unroll
      for (int r = 0; r < 4; r++)
        sc[t][r] = kvalid ? sA[t][r] * 0.125f : -1e9f;
    }
    float mx[4], nn[4], cor[4], sum[4];
#pragma unroll
    for (int r = 0; r < 4; r++) {
      mx[r] = fmaxf(fmaxf(sc[0][r], sc[1][r]), fmaxf(sc[2][r], sc[3][r]));
      mx[r] = fmaxf(mx[r], __shfl_xor(mx[r], 1, 64));
      mx[r] = fmaxf(mx[r], __shfl_xor(mx[r], 2, 64));
      mx[r] = fmaxf(mx[r], __shfl_xor(mx[r], 4, 64));
      mx[r] = fmaxf(mx[r], __shfl_xor(mx[r], 8, 64));
      nn[r] = fmaxf(mm[r], mx[r]);
      cor[r] = __expf(mm[r] - nn[r]);
      mm[r] = nn[r];
    }
    float pp[4][4];
#pragma unroll
    for (int t = 0; t < 4; t++)
#pragma unroll
      for (int r = 0; r < 4; r++) pp[t][r] = __expf(sc[t][r] - nn[r]);
#pragma unroll
    for (int r = 0; r < 4; r++) {
      sum[r] = (pp[0][r] + pp[1][r]) + (pp[2][r] + pp[3][r]);
      sum[r] += __shfl_xor(sum[r], 1, 64);
      sum[r] += __shfl_xor(sum[r], 2, 64);
      sum[r] += __shfl_xor(sum[r], 4, 64);
      sum[r] += __shfl_xor(sum[r], 8, 64);
      ll[r] = ll[r] * cor[r] + sum[r];
    }
    // ---- P hi into the (dead-Q) QP buffer ----
#pragma unroll
    for (int t = 0; t < 4; t++) {
#pragma unroll
      for (int r = 0; r < 4; r++) {
        accO[t][r] *= cor[r];
        int row = wave * 16 + lg * 4 + r, col = t * 16 + lm;
        QP[SWZ(row, col)] = bfh(pp[t][r]);
      }
    }

    // ---- PV: 1 term (Ph*Vh) ----
    bf16x8 pAh[2];
#pragma unroll
    for (int s = 0; s < 2; s++)
      pAh[s] = *(const bf16x8*)&QP[SWZ(wave * 16 + lm, s * 32 + lg * 8)];
    __builtin_amdgcn_s_setprio(1);
#pragma unroll
    for (int t = 0; t < 4; t++) {
#pragma unroll
      for (int s = 0; s < 2; s++) {
        bf16x8 vb = *(const bf16x8*)&VT[SWZ(t * 16 + lm, s * 32 + lg * 8)];
        accO[t] = __builtin_amdgcn_mfma_f32_16x16x32_bf16(pAh[s], vb, accO[t], 0, 0, 0);
      }
    }
    __builtin_amdgcn_s_setprio(0);
  }
#undef KV_LOAD
#undef KV_WRITE

#pragma unroll
  for (int t = 0; t < 4; t++) {
#pragma unroll
    for (int r = 0; r < 4; r++) {
      int row = q0 + wave * 16 + lg * 4 + r;
      if (row < len)
        atomicAdd(&OH[(size_t)toks[row] * D_ + h * DH_ + t * 16 + lm],
                  accO[t][r] / ll[r]);
    }
  }
}

// ---------------------------------------------------------------------------
extern "C" void kernel_launch(void* const* d_in, const int* in_sizes, int n_in,
                              void* d_out, int out_size, void* d_ws, size_t ws_size,
                              hipStream_t stream) {
  (void)in_sizes; (void)n_in; (void)out_size; (void)ws_size;
  const float* q_in = (const float*)d_in[0];
  const float* k_in = (const float*)d_in[1];
  const float* v_in = (const float*)d_in[2];
  const int* seqlens = (const int*)d_in[3];
  const int* gidx    = (const int*)d_in[4];
  const float* Wq = (const float*)d_in[5];
  const float* Wk = (const float*)d_in[6];
  const float* Wv = (const float*)d_in[7];
  const float* Wo = (const float*)d_in[8];
  float* out = (float*)d_out;

  unsigned short* Qh = (unsigned short*)d_ws;
  unsigned short* Ql = Qh + NELEM_;      // unused
  unsigned short* Kh = Ql + NELEM_;
  unsigned short* Kl = Kh + NELEM_;      // v-split hi staging
  unsigned short* Vh = Kl + NELEM_;
  unsigned short* Vl = Vh + NELEM_;      // q-split hi staging
  float* OH = (float*)(Vl + NELEM_);
  float* WS = OH + NELEM_;               // 2M f32 = 4 x 1M ushort (W his)
  float* FE = WS + (4 << 19);
  float* FQ = FE + (size_t)TTOT_ * DH_;
  float* FK = FQ + (size_t)TTOT_ * DH_;
  float* Wqm = FK + (size_t)TTOT_ * DH_;
  float* Wkm = Wqm + 64 * 1024;
  int* cT = (int*)(Wkm + 64 * 1024);
  int* cL = cT + MAXCL_ * MAXLEN_;
  int* tC = cL + MAXCL_;

  unsigned short* QSh = Vl;                    // q split-hi (Vl slab)
  unsigned short* KSh = (unsigned short*)out;  // k split-hi (d_out, dead until final GEMM)
  unsigned short* VSh = Kl;                    // v split-hi (Kl slab)
  unsigned short* WqH = (unsigned short*)WS;
  unsigned short* WkH = WqH + (1 << 20);
  unsigned short* WvH = WkH + (1 << 20);
  unsigned short* WoH = WvH + (1 << 20);

  hipMemsetAsync(tC, 0, TTOT_ * sizeof(int), stream);

  // ---- wmean (exact f32, feats dependency) ----
  wmean2<<<dim3(256, 2), 256, 0, stream>>>(Wq, Wk, Wqm, Wkm);

  // ---- feats GEMM (256 blocks) + all conversions (fills idle CUs) ----
  feats_conv<<<256 + (4 * N4W_ + 3 * N4IN_ + 255) / 256, 256, 0, stream>>>(
      q_in, k_in, v_in, Wqm, Wkm, FQ, FK,
      Wq, Wk, Wv, Wo, WqH, WkH, WvH, WoH, QSh, KSh, VSh);

  l2comb<<<TTOT_ / 4, 256, 0, stream>>>(FQ, FK, FE);

  // ---- routing + Q/K/V GEMMs + OH zeroing fused ----
  fused_qkvr<<<4 + 1536 + 2048, 1024, 0, stream>>>(QSh, WqH, Qh,
                                                   KSh, WkH, Kh,
                                                   VSh, WvH, Vh,
                                                   OH,
                                                   FE, seqlens, gidx, cT, cL, tC);

  // ---- attention (OH already zeroed inside fused_qkvr) ----
  attn_kernel<<<7 * H_ * MAXCL_, 256, 0, stream>>>(
      Qh, Kh, Vh, cT, cL, OH);

  // ---- output GEMM with fused normalize (512 blocks) ----
  gemm_on<<<512, 256, 0, stream>>>(OH, tC, WoH, out);
}

// Round 29
// 297.311 us; speedup vs baseline: 1.0394x; 1.0394x over previous
//
#include <hip/hip_runtime.h>
#include <math.h>

#define S_ 4
#define L_ 2048
#define D_ 1024
#define H_ 16
#define DH_ 64
#define TTOT_ 8192
#define WCL_ 384
#define KMAX_ 16
#define MAXCL_ (S_*KMAX_)
#define MAXLEN_ (WCL_+1)   // 385
#define LSCAP_ 2048        // benchmark seqlens are fixed at L=2048
#define NELEM_ ((size_t)TTOT_*(size_t)D_)

typedef __attribute__((ext_vector_type(8))) short bf16x8;
typedef __attribute__((ext_vector_type(4))) float f32x4;
typedef __attribute__((ext_vector_type(4))) unsigned short u16x4;

// bf16 helpers (RNE)
__device__ __forceinline__ unsigned short bfh(float x) {
  unsigned u = __float_as_uint(x);
  return (unsigned short)((u + 0x7FFFu + ((u >> 16) & 1u)) >> 16);
}
__device__ __forceinline__ float bff(unsigned short h) {
  return __uint_as_float(((unsigned)h) << 16);
}
__device__ __forceinline__ unsigned pk2(unsigned short a, unsigned short b) {
  return (unsigned)a | ((unsigned)b << 16);
}
// XOR swizzle on ushort index within [row][64] tiles (16B-chunk granularity)
#define SWZ(r, c) (((r) << 6) + ((c) ^ (((r) & 7) << 3)))

__device__ __forceinline__ void glds16(const void* g, void* l) {
  __builtin_amdgcn_global_load_lds(
      (const __attribute__((address_space(1))) unsigned int*)g,
      (__attribute__((address_space(3))) unsigned int*)l, 16, 0, 0);
}

#define N4W_ ((1 << 20) / 4)
#define N4IN_ ((int)(NELEM_ / 4))
#define NWM_ (64 * 1024)
#define NTC4_ (TTOT_ / 4)

// ---------------------------------------------------------------------------
// Fused Wm[d][k] = (1/16) sum_h W[h*64+d][k] for both Wq and Wk (grid.y)
// (exact f32 routing path — must run before feats)
// ---------------------------------------------------------------------------
__global__ __launch_bounds__(256)
void wmean2(const float* __restrict__ Wq, const float* __restrict__ Wk,
            float* __restrict__ Wqm, float* __restrict__ Wkm) {
  const float* __restrict__ W = blockIdx.y ? Wk : Wq;
  float* __restrict__ Wm = blockIdx.y ? Wkm : Wqm;
  int i = blockIdx.x * 256 + threadIdx.x;
  if (i >= NWM_) return;
  int d = i >> 10, kk = i & 1023;
  float s = 0.f;
#pragma unroll
  for (int h = 0; h < 16; h++) s += W[(size_t)(h * 64 + d) * 1024 + kk];
  Wm[i] = s * (1.0f / 16.0f);
}

// ---------------------------------------------------------------------------
// Fused feats GEMM + conversions + tC zeroing: blocks 0..255 = exact
// gemm_feats body; blocks 256+ = W hi + q/k/v hi conversions + tC memset.
// ---------------------------------------------------------------------------
__global__ __launch_bounds__(256)
void feats_conv(const float* __restrict__ q_in, const float* __restrict__ k_in,
                const float* __restrict__ v_in,
                const float* __restrict__ Wqm, const float* __restrict__ Wkm,
                float* __restrict__ FQ, float* __restrict__ FK,
                const float* __restrict__ Wq, const float* __restrict__ Wk,
                const float* __restrict__ Wv, const float* __restrict__ Wo,
                unsigned short* __restrict__ WqH, unsigned short* __restrict__ WkH,
                unsigned short* __restrict__ WvH, unsigned short* __restrict__ WoH,
                unsigned short* __restrict__ QSh, unsigned short* __restrict__ KSh,
                unsigned short* __restrict__ VSh, int* __restrict__ tC) {
  if (blockIdx.x < 256) {
    // ---- feats GEMM (exact f32; identical to gemm_feats) ----
    const int by = blockIdx.x >> 7;              // 0: q, 1: k
    const float* __restrict__ A = by ? k_in : q_in;
    const float* __restrict__ B = by ? Wkm : Wqm;
    float* __restrict__ C = by ? FK : FQ;
    const int Kd = 1024, N = 64;
    __shared__ float As[16][68];
    __shared__ float Bs[16][68];
    const int tx = threadIdx.x & 15, ty = threadIdx.x >> 4;
    const int m0 = (blockIdx.x & 127) * 64;
    const int lr = threadIdx.x >> 2, lc = threadIdx.x & 3;
    float acc[4][4] = {};
    for (int k0 = 0; k0 < Kd; k0 += 16) {
      __syncthreads();
      float4 a4 = *(const float4*)(A + (size_t)(m0 + lr) * Kd + k0 + lc * 4);
      float4 b4 = *(const float4*)(B + (size_t)lr * Kd + k0 + lc * 4);
      As[lc*4+0][lr] = a4.x; As[lc*4+1][lr] = a4.y; As[lc*4+2][lr] = a4.z; As[lc*4+3][lr] = a4.w;
      Bs[lc*4+0][lr] = b4.x; Bs[lc*4+1][lr] = b4.y; Bs[lc*4+2][lr] = b4.z; Bs[lc*4+3][lr] = b4.w;
      __syncthreads();
#pragma unroll
      for (int kk = 0; kk < 16; kk++) {
        float4 av = *(const float4*)&As[kk][ty * 4];
        float4 bv = *(const float4*)&Bs[kk][tx * 4];
        float aa[4] = {av.x, av.y, av.z, av.w};
        float bb[4] = {bv.x, bv.y, bv.z, bv.w};
#pragma unroll
        for (int i = 0; i < 4; i++)
#pragma unroll
          for (int j = 0; j < 4; j++) acc[i][j] += aa[i] * bb[j];
      }
    }
#pragma unroll
    for (int i = 0; i < 4; i++)
#pragma unroll
      for (int j = 0; j < 4; j++)
        C[(size_t)(m0 + ty * 4 + i) * N + (tx * 4 + j)] = acc[i][j];
    return;
  }
  // ---- conversion blocks ----
  int i = (blockIdx.x - 256) * 256 + threadIdx.x;
  if (i < 4 * N4W_) {
    int w = i / N4W_, j = i % N4W_;
    const float* src = (w == 0) ? Wq : (w == 1) ? Wk : (w == 2) ? Wv : Wo;
    unsigned short* dst = (w == 0) ? WqH : (w == 1) ? WkH : (w == 2) ? WvH : WoH;
    float4 v = ((const float4*)src)[j];
    *(uint2*)&dst[(size_t)j * 4] =
        make_uint2(pk2(bfh(v.x), bfh(v.y)), pk2(bfh(v.z), bfh(v.w)));
    return;
  }
  i -= 4 * N4W_;
  if (i < 3 * N4IN_) {
    int w = i / N4IN_, j = i % N4IN_;
    const float* src = (w == 0) ? q_in : (w == 1) ? k_in : v_in;
    unsigned short* dh = (w == 0) ? QSh : (w == 1) ? KSh : VSh;
    float4 v = ((const float4*)src)[j];
    *(uint2*)&dh[(size_t)j * 4] =
        make_uint2(pk2(bfh(v.x), bfh(v.y)), pk2(bfh(v.z), bfh(v.w)));
    return;
  }
  i -= 3 * N4IN_;
  if (i >= NTC4_) return;
  ((uint4*)tC)[i] = (uint4){0u, 0u, 0u, 0u};
}

// ---------------------------------------------------------------------------
// 1-term bf16 GEMM core (a_hi * W_hi), hi-only bf16 C. 32 KB LDS; 256 thr.
// M = TTOT_, N = Kd = D_. Requires block index b in [0, 512).
// ---------------------------------------------------------------------------
__device__ __forceinline__
void gemm1_body(const unsigned short* __restrict__ Ah,
                const unsigned short* __restrict__ Bh,
                unsigned short* __restrict__ Ch,
                int b, unsigned char* smem) {
  const int Kd = D_, N = D_;
  const int m0 = (b & 63) * 128, n0 = (b >> 6) * 128;
  unsigned short* LA = (unsigned short*)smem;    // 16 KB
  unsigned short* LB = LA + 8192;                // 16 KB
  const int tid = threadIdx.x, wave = tid >> 6, lane = tid & 63;
  const int lm = lane & 15, lg = lane >> 4;
  const int wr = wave >> 1, wc = wave & 1;
  const int lrow = lane >> 3;
  const int lchk = (lane & 7) ^ lrow;
  f32x4 acc[4][4];
#pragma unroll
  for (int i = 0; i < 4; i++)
#pragma unroll
    for (int j = 0; j < 4; j++) acc[i][j] = (f32x4){0.f, 0.f, 0.f, 0.f};
  for (int k0 = 0; k0 < Kd; k0 += 64) {
    __syncthreads();
#pragma unroll
    for (int i = 0; i < 4; i++) {
      const int r = wave * 32 + i * 8;
      const size_t ga = (size_t)(m0 + r + lrow) * Kd + k0 + lchk * 8;
      const size_t gb = (size_t)(n0 + r + lrow) * Kd + k0 + lchk * 8;
      glds16(&Ah[ga], &LA[r * 64]);
      glds16(&Bh[gb], &LB[r * 64]);
    }
    __syncthreads();
#pragma unroll
    for (int s = 0; s < 2; s++) {
      bf16x8 ah[4], bh[4];
#pragma unroll
      for (int i = 0; i < 4; i++) {
        const int ra = wr * 64 + i * 16 + lm;
        const int ca = ((s * 4 + lg) ^ (ra & 7)) * 8;
        ah[i] = *(const bf16x8*)&LA[ra * 64 + ca];
        const int rb = wc * 64 + i * 16 + lm;
        const int cb = ((s * 4 + lg) ^ (rb & 7)) * 8;
        bh[i] = *(const bf16x8*)&LB[rb * 64 + cb];
      }
#pragma unroll
      for (int i = 0; i < 4; i++)
#pragma unroll
        for (int j = 0; j < 4; j++)
          acc[i][j] = __builtin_amdgcn_mfma_f32_16x16x32_bf16(ah[i], bh[j], acc[i][j], 0, 0, 0);
    }
  }
#pragma unroll
  for (int i = 0; i < 4; i++)
#pragma unroll
    for (int j = 0; j < 4; j++) {
      const int rowb = m0 + wr * 64 + i * 16 + lg * 4;
      const int col = n0 + wc * 64 + j * 16 + lm;
#pragma unroll
      for (int r = 0; r < 4; r++)
        Ch[(size_t)(rowb + r) * N + col] = bfh(acc[i][j][r]);
    }
}

// ---------------------------------------------------------------------------
// Wo GEMM with fused normalize: A = bfh(OH[row]*1/max(cnt,1)) staged via
// registers + ds_write (bit-identical to norm_h + gemm_o1). GRID = 512.
// ---------------------------------------------------------------------------
__global__ __launch_bounds__(256)
void gemm_on(const float* __restrict__ OHf, const int* __restrict__ cnt,
             const unsigned short* __restrict__ Bh,
             float* __restrict__ C) {
  __shared__ __align__(16) unsigned short LA[128 * 64];
  __shared__ __align__(16) unsigned short LB[128 * 64];
  const int Kd = D_, N = D_;
  const int tid = threadIdx.x, wave = tid >> 6, lane = tid & 63;
  const int lm = lane & 15, lg = lane >> 4;
  const int m0 = (blockIdx.x & 63) * 128, n0 = (blockIdx.x >> 6) * 128;
  const int wr = wave >> 1, wc = wave & 1;
  const int lrow = lane >> 3;
  const int lchk = (lane & 7) ^ lrow;
  f32x4 acc[4][4];
#pragma unroll
  for (int i = 0; i < 4; i++)
#pragma unroll
    for (int j = 0; j < 4; j++) acc[i][j] = (f32x4){0.f, 0.f, 0.f, 0.f};
  for (int k0 = 0; k0 < Kd; k0 += 64) {
    __syncthreads();
#pragma unroll
    for (int i = 0; i < 4; i++) {
      const int r = wave * 32 + i * 8;
      const int arow = m0 + r + lrow;
      const float* asrc = OHf + (size_t)arow * Kd + k0 + lchk * 8;
      float4 a0 = *(const float4*)asrc;
      float4 a1 = *(const float4*)(asrc + 4);
      int cc = cnt[arow];
      float sc = 1.0f / (float)(cc > 1 ? cc : 1);
      uint4 pk;
      pk.x = pk2(bfh(a0.x * sc), bfh(a0.y * sc));
      pk.y = pk2(bfh(a0.z * sc), bfh(a0.w * sc));
      pk.z = pk2(bfh(a1.x * sc), bfh(a1.y * sc));
      pk.w = pk2(bfh(a1.z * sc), bfh(a1.w * sc));
      *(uint4*)&LA[r * 64 + lane * 8] = pk;
      const size_t gb = (size_t)(n0 + r + lrow) * Kd + k0 + lchk * 8;
      glds16(&Bh[gb], &LB[r * 64]);
    }
    __syncthreads();
#pragma unroll
    for (int s = 0; s < 2; s++) {
      bf16x8 ah[4], bh[4];
#pragma unroll
      for (int i = 0; i < 4; i++) {
        const int ra = wr * 64 + i * 16 + lm;
        const int ca = ((s * 4 + lg) ^ (ra & 7)) * 8;
        ah[i] = *(const bf16x8*)&LA[ra * 64 + ca];
        const int rb = wc * 64 + i * 16 + lm;
        const int cb = ((s * 4 + lg) ^ (rb & 7)) * 8;
        bh[i] = *(const bf16x8*)&LB[rb * 64 + cb];
      }
#pragma unroll
      for (int i = 0; i < 4; i++)
#pragma unroll
        for (int j = 0; j < 4; j++)
          acc[i][j] = __builtin_amdgcn_mfma_f32_16x16x32_bf16(ah[i], bh[j], acc[i][j], 0, 0, 0);
    }
  }
#pragma unroll
  for (int i = 0; i < 4; i++)
#pragma unroll
    for (int j = 0; j < 4; j++) {
      const int rowb = m0 + wr * 64 + i * 16 + lg * 4;
      const int col = n0 + wc * 64 + j * 16 + lm;
#pragma unroll
      for (int r = 0; r < 4; r++)
        C[(size_t)(rowb + r) * N + col] = acc[i][j][r];
    }
}

// ---------------------------------------------------------------------------
// FE[t] = 0.5*(l2n(FQ[t]) + l2n(FK[t]))   (one wave per token; unchanged)
// ---------------------------------------------------------------------------
__global__ __launch_bounds__(256)
void l2comb(const float* __restrict__ FQ, const float* __restrict__ FK,
            float* __restrict__ FE) {
  int t = blockIdx.x * 4 + (threadIdx.x >> 6);
  int lane = threadIdx.x & 63;
  if (t >= TTOT_) return;
  float q = FQ[(size_t)t * 64 + lane], k = FK[(size_t)t * 64 + lane];
  float q2 = q * q, k2 = k * k;
#pragma unroll
  for (int m = 1; m < 64; m <<= 1) {
    q2 += __shfl_xor(q2, m, 64);
    k2 += __shfl_xor(k2, m, 64);
  }
  FE[(size_t)t * 64 + lane] =
      0.5f * (q / (sqrtf(q2) + 1e-6f) + k / (sqrtf(k2) + 1e-6f));
}

// ---------------------------------------------------------------------------
// Routing body, 1024 threads — EXACT R10/R13 numerics (R27 assignment form:
// hoisted fr[16], j-loop — R28's c4-outer regressed and is reverted).
// R29: LDS compacted to 22.7 KB (LSCAP=2048 -> keys 16K, assign 2K, cent 4K)
// so the kernel's static smem is 32 KB -> GEMM blocks get 5/CU (was 3/CU).
// Centroid fstage chunk 128 -> 64 rows (ascending-i order kept, bit-identical).
// Keeps R24 wave-sync bitonic + setprio.
// ---------------------------------------------------------------------------
__device__ void routing_body(int s, const float* __restrict__ FE,
                             const int* __restrict__ seqlens,
                             const int* __restrict__ gidx, int* __restrict__ cT,
                             int* __restrict__ cL, int* __restrict__ tC,
                             unsigned char* smem) {
  __builtin_amdgcn_s_setprio(1);   // routing is the latency-critical path
  unsigned long long* keys = (unsigned long long*)smem;        // 16 KB (NP2<=2048)
  unsigned char* assign = smem + 16384;                        // 2 KB
  float (*cent)[64] = (float(*)[64])(smem + 18432);            // 4 KB
  int* cnt1 = (int*)(smem + 22528);
  int* cnt2 = cnt1 + KMAX_;
  int* starts = cnt2 + KMAX_;
  float* fstage = (float*)smem;    // aliases keys: dead during centroid phase

  const int tid = threadIdx.x;
  int a = 0;
  for (int t = 0; t < s; t++) a += seqlens[t];
  int Ls = seqlens[s];
  if (Ls > LSCAP_) Ls = LSCAP_;
  for (int cs = tid; cs < KMAX_; cs += 1024) cL[s * KMAX_ + cs] = 0;
  if (Ls <= 0) return;

  int wloc = Ls < WCL_ ? Ls : WCL_;
  if (wloc < 1) wloc = 1;
  int k = (Ls + wloc - 1) / wloc;
  if (k < 1) k = 1;
  if (k > KMAX_) k = KMAX_;

  if (tid < k * 64) {
    int j = tid >> 6, d = tid & 63;
    double step = (k > 1) ? (double)(Ls - 1) / (double)(k - 1) : 0.0;
    long ii = (long)rint(step * (double)j);
    if (ii < 0) ii = 0;
    if (ii > Ls - 1) ii = Ls - 1;
    cent[j][d] = FE[(size_t)(a + ii) * DH_ + d];
  }
  if (tid < KMAX_) { cnt1[tid] = 0; cnt2[tid] = 0; }
  __syncthreads();

  // ---- assignment pass 1 (hoisted f) + ballot counting ----
  for (int base2 = 0; base2 < Ls; base2 += 1024) {
    int i = base2 + tid;
    int aj = -1;
    if (i < Ls) {
      const float4* f4 = (const float4*)(FE + (size_t)(a + i) * DH_);
      float4 fr[16];
#pragma unroll
      for (int c4 = 0; c4 < 16; c4++) fr[c4] = f4[c4];
      float best = -1e30f; int bj = 0;
      for (int j = 0; j < k; j++) {
        float sd = 0.f;
#pragma unroll
        for (int c4 = 0; c4 < 16; c4++) {
          float4 cv = *(const float4*)&cent[j][c4 * 4];
          sd += fr[c4].x * cv.x; sd += fr[c4].y * cv.y;
          sd += fr[c4].z * cv.z; sd += fr[c4].w * cv.w;
        }
        if (sd > best) { best = sd; bj = j; }
      }
      assign[i] = (unsigned char)bj;
      aj = bj;
    }
    for (int j = 0; j < k; j++) {
      unsigned long long m = __ballot(aj == j);
      if ((tid & 63) == 0 && m) atomicAdd(&cnt1[j], (int)__popcll(m));
    }
  }
  __syncthreads();

  // ---- exact np.add.at centroid accumulation, LDS-chunked (64 rows/chunk).
  float csum_acc = 0.f;
  const int jj = tid >> 6, dd = tid & 63;
  for (int base = 0; base < Ls; base += 64) {
    const int cr = (Ls - base < 64) ? (Ls - base) : 64;
    __syncthreads();   // accumulators done with previous chunk
    {
      int f = tid;     // 1024 float4s = 64 rows x 16
      int row = f >> 4;
      if (row < cr)
        ((float4*)fstage)[f] =
            *(const float4*)(FE + (size_t)(a + base + row) * DH_ + (f & 15) * 4);
    }
    __syncthreads();   // chunk staged
    if (jj < k) {
      const float* fp = fstage + dd;
      int i = 0;
      for (; i + 16 <= cr; i += 16) {
        float v[16];
#pragma unroll
        for (int u = 0; u < 16; u++) v[u] = fp[(i + u) * DH_];
        unsigned char aa[16];
#pragma unroll
        for (int u = 0; u < 16; u++) aa[u] = assign[base + i + u];
#pragma unroll
        for (int u = 0; u < 16; u++)
          csum_acc += (aa[u] == (unsigned char)jj) ? v[u] : 0.0f;
      }
      for (; i < cr; i++)
        csum_acc += (assign[base + i] == (unsigned char)jj) ? fp[i * DH_] : 0.0f;
    }
  }
  __syncthreads();
  if (tid < k * 64) {
    float v = csum_acc / fmaxf((float)cnt1[jj], 1.0f);
    float sq = v * v;
#pragma unroll
    for (int m = 1; m < 64; m <<= 1) sq += __shfl_xor(sq, m, 64);
    cent[jj][dd] = v / (sqrtf(sq) + 1e-6f);
  }
  __syncthreads();

  // ---- assignment pass 2 + sort keys (hoisted f) + ballot counting ----
  int NP2 = 1;
  while (NP2 < Ls) NP2 <<= 1;
  for (int base2 = 0; base2 < NP2; base2 += 1024) {
    int i = base2 + tid;
    int aj = -1;
    if (i < NP2) {
      unsigned long long key;
      if (i < Ls) {
        const float4* f4 = (const float4*)(FE + (size_t)(a + i) * DH_);
        float4 fr[16];
#pragma unroll
        for (int c4 = 0; c4 < 16; c4++) fr[c4] = f4[c4];
        float best = -1e30f; int bj = 0;
        for (int j = 0; j < k; j++) {
          float sd = 0.f;
#pragma unroll
          for (int c4 = 0; c4 < 16; c4++) {
            float4 cv = *(const float4*)&cent[j][c4 * 4];
            sd += fr[c4].x * cv.x; sd += fr[c4].y * cv.y;
            sd += fr[c4].z * cv.z; sd += fr[c4].w * cv.w;
          }
          if (sd > best) { best = sd; bj = j; }
        }
        aj = bj;
        unsigned int u = __float_as_uint(best);
        unsigned int ord = (u & 0x80000000u) ? ~u : (u | 0x80000000u);
        unsigned int dsc = ~ord;
        key = ((unsigned long long)bj << 45) |
              ((unsigned long long)dsc << 13) | (unsigned long long)i;
      } else {
        key = ~0ull;
      }
      keys[i] = key;
    }
    for (int j = 0; j < k; j++) {
      unsigned long long m = __ballot(aj == j);
      if ((tid & 63) == 0 && m) atomicAdd(&cnt2[j], (int)__popcll(m));
    }
  }
  __syncthreads();

  // ---- bitonic sort: full barrier only when partners cross waves (st>=64);
  // intra-wave stages rely on per-wave in-order DS + lgkmcnt(0). ----
  for (int len2 = 2; len2 <= NP2; len2 <<= 1) {
    for (int st = len2 >> 1; st > 0; st >>= 1) {
      if (st >= 64) {
        __syncthreads();
      } else {
        asm volatile("s_waitcnt lgkmcnt(0)" ::: "memory");
      }
      for (int i = tid; i < NP2; i += 1024) {
        int j = i ^ st;
        if (j > i) {
          unsigned long long x = keys[i], y = keys[j];
          bool asc = ((i & len2) == 0);
          if ((x > y) == asc) { keys[i] = y; keys[j] = x; }
        }
      }
    }
  }
  __syncthreads();
  if (tid == 0) {
    starts[0] = 0;
    for (int j = 0; j < k; j++) starts[j + 1] = starts[j] + cnt2[j];
  }
  __syncthreads();

  const int g = gidx[s];
  int cOut = 0;
  for (int j = 0; j < k; j++) {
    int cj = cnt2[j];
    if (cj <= 0) continue;
    int keep = cj < wloc ? cj : wloc;
    int slot = s * KMAX_ + cOut;
    for (int p = tid; p < keep; p += 1024) {
      int token = a + (int)(keys[starts[j] + p] & 0x1FFFull);
      cT[slot * MAXLEN_ + p] = token;
      atomicAdd(&tC[token], 1);
    }
    if (tid == 0) {
      cT[slot * MAXLEN_ + keep] = g;
      atomicAdd(&tC[g], 1);
      cL[slot] = keep + 1;
    }
    cOut++;
  }
}

// ---------------------------------------------------------------------------
// Mega-fused, 32 KB static LDS (GEMM blocks now 5/CU): blocks 0..3 routing;
// 4..515 Q-GEMM; 516..1027 K-GEMM; 1028..1539 V-GEMM; 1540..3587 OH-zeroing.
// ---------------------------------------------------------------------------
__global__ __launch_bounds__(1024)
void fused_qkvr(const unsigned short* __restrict__ QAh,
                const unsigned short* __restrict__ WqH,
                unsigned short* __restrict__ Qh,
                const unsigned short* __restrict__ KAh,
                const unsigned short* __restrict__ WkH,
                unsigned short* __restrict__ Kh,
                const unsigned short* __restrict__ VAh,
                const unsigned short* __restrict__ WvH,
                unsigned short* __restrict__ Vh,
                float* __restrict__ OHz,
                const float* __restrict__ FE, const int* __restrict__ seqlens,
                const int* __restrict__ gidx, int* __restrict__ cT,
                int* __restrict__ cL, int* __restrict__ tC) {
  __shared__ __align__(16) unsigned char smem[32768];
  if (blockIdx.x < 4) {
    routing_body(blockIdx.x, FE, seqlens, gidx, cT, cL, tC, smem);
    return;
  }
  int b = blockIdx.x - 4;
  if (b >= 1536) {
    // OH zeroing: 2048 blocks x 1024 threads x 16B = 32 MB
    size_t o = (size_t)(b - 1536) * 1024 + threadIdx.x;
    ((float4*)OHz)[o] = (float4){0.f, 0.f, 0.f, 0.f};
    return;
  }
  if (threadIdx.x >= 256) return;     // free 12 of 16 waves
  if (b < 512) {
    gemm1_body(QAh, WqH, Qh, b, smem);
  } else if (b < 1024) {
    gemm1_body(KAh, WkH, Kh, b - 512, smem);
  } else {
    gemm1_body(VAh, WvH, Vh, b - 1024, smem);
  }
}

// ---------------------------------------------------------------------------
// MFMA flash attention v7 (unchanged): Q/K/V hi-only (QK: qh*kh; PV: ph*vh).
// XCD-grouped 1D grid, async reg-staged K/V, setprio, P bf16.
// LDS: toks 1.5K + QP 8K + KT 8K + VT 8K = 25.5 KB.
// ---------------------------------------------------------------------------
__global__ __launch_bounds__(256)
void attn_kernel(const unsigned short* __restrict__ Qh,
                 const unsigned short* __restrict__ Kh,
                 const unsigned short* __restrict__ Vh,
                 const int* __restrict__ cT, const int* __restrict__ cL,
                 float* __restrict__ OH) {
  const int flat = blockIdx.x;
  const int xcd = flat & 7;
  const int i8 = flat >> 3;              // 0..895
  const int qc = i8 % 7;
  const int g = xcd + 8 * (i8 / 7);      // 0..1023, g%8==xcd
  const int h = g & 15, c = g >> 4;

  const int len = cL[c];
  const int q0 = qc * 64;
  if (len <= 0 || q0 >= len) return;

  __shared__ int toks[MAXLEN_];
  __shared__ __align__(16) unsigned short QP[4096];  // Q hi tile -> P hi
  __shared__ __align__(16) unsigned short KT[4096];  // K hi
  __shared__ __align__(16) unsigned short VT[4096];  // V^T hi

  const int tid = threadIdx.x, wave = tid >> 6, lane = tid & 63;
  const int lm = lane & 15, lg = lane >> 4;
  const int lr8 = lane >> 3;            // row within 8-row slab (Q glds)
  const int lc8 = (lane & 7) ^ lr8;     // pre-swizzled source chunk (Q glds)

  const int krow = tid >> 2;
  const int kc = (tid & 3) * 16;
  const int dg = tid & 15, kg = tid >> 4;
  const int vd0 = dg * 4;

  for (int i = tid; i < len; i += 256) toks[i] = cT[c * MAXLEN_ + i];
  __syncthreads();

  uint4 ka0, ka1;
  u16x4 va0, va1, va2, va3;

#define KV_LOAD(mt_) do {                                                      \
    int kr_ = (mt_) * 64 + krow;                                               \
    int tk_ = toks[kr_ < len ? kr_ : 0];                                       \
    const unsigned short* kph = Kh + (size_t)tk_ * D_ + h * DH_ + kc;          \
    ka0 = *(const uint4*)(kph);  ka1 = *(const uint4*)(kph + 8);               \
    int vr_ = (mt_) * 64 + kg * 4;                                             \
    int t0_ = toks[vr_ + 0 < len ? vr_ + 0 : 0];                               \
    int t1_ = toks[vr_ + 1 < len ? vr_ + 1 : 0];                               \
    int t2_ = toks[vr_ + 2 < len ? vr_ + 2 : 0];                               \
    int t3_ = toks[vr_ + 3 < len ? vr_ + 3 : 0];                               \
    size_t off_ = (size_t)h * DH_ + vd0;                                       \
    va0 = *(const u16x4*)(Vh + (size_t)t0_ * D_ + off_);                       \
    va1 = *(const u16x4*)(Vh + (size_t)t1_ * D_ + off_);                       \
    va2 = *(const u16x4*)(Vh + (size_t)t2_ * D_ + off_);                       \
    va3 = *(const u16x4*)(Vh + (size_t)t3_ * D_ + off_);                       \
  } while (0)

#define KV_WRITE() do {                                                        \
    *(uint4*)&KT[SWZ(krow, kc)] = ka0;                                         \
    *(uint4*)&KT[SWZ(krow, kc + 8)] = ka1;                                     \
    _Pragma("unroll") for (int dd = 0; dd < 4; dd++) {                         \
      *(uint2*)&VT[SWZ(vd0 + dd, kg * 4)] =                                    \
          make_uint2(pk2(va0[dd], va1[dd]), pk2(va2[dd], va3[dd]));            \
    }                                                                          \
  } while (0)

  // ---- stage Q tile once (glds, source-swizzled, hi-only) ----
#pragma unroll
  for (int i = 0; i < 2; i++) {
    int slab = wave * 2 + i;                     // 0..7
    int r8 = slab * 8;
    int row = q0 + r8 + lr8;
    int tok = toks[row < len ? row : 0];
    glds16(Qh + (size_t)tok * D_ + h * DH_ + lc8 * 8, &QP[r8 * 64]);
  }
  KV_LOAD(0);
  __syncthreads();

  bf16x8 qAh[2];
#pragma unroll
  for (int s = 0; s < 2; s++)
    qAh[s] = *(const bf16x8*)&QP[SWZ(wave * 16 + lm, s * 32 + lg * 8)];

  f32x4 accO[4];
#pragma unroll
  for (int t = 0; t < 4; t++) accO[t] = (f32x4){0.f, 0.f, 0.f, 0.f};
  float mm[4] = {-INFINITY, -INFINITY, -INFINITY, -INFINITY};
  float ll[4] = {0.f, 0.f, 0.f, 0.f};

  const int ntile = (len + 63) >> 6;
  for (int mt = 0; mt < ntile; mt++) {
    __syncthreads();
    KV_WRITE();
    __syncthreads();
    if (mt + 1 < ntile) KV_LOAD(mt + 1);

    f32x4 sA[4];
#pragma unroll
    for (int t = 0; t < 4; t++) sA[t] = (f32x4){0.f, 0.f, 0.f, 0.f};
    __builtin_amdgcn_s_setprio(1);
#pragma unroll
    for (int t = 0; t < 4; t++) {
#pragma unroll
      for (int s = 0; s < 2; s++) {
        bf16x8 kb = *(const bf16x8*)&KT[SWZ(t * 16 + lm, s * 32 + lg * 8)];
        sA[t] = __builtin_amdgcn_mfma_f32_16x16x32_bf16(qAh[s], kb, sA[t], 0, 0, 0);
      }
    }
    __builtin_amdgcn_s_setprio(0);

    float sc[4][4];
#pragma unroll
    for (int t = 0; t < 4; t++) {
      bool kvalid = (mt * 64 + t * 16 + lm) < len;
#pragma unroll
      for (int r = 0; r < 4; r++)
        sc[t][r] = kvalid ? sA[t][r] * 0.125f : -1e9f;
    }
    float mx[4], nn[4], cor[4], sum[4];
#pragma unroll
    for (int r = 0; r < 4; r++) {
      mx[r] = fmaxf(fmaxf(sc[0][r], sc[1][r]), fmaxf(sc[2][r], sc[3][r]));
      mx[r] = fmaxf(mx[r], __shfl_xor(mx[r], 1, 64));
      mx[r] = fmaxf(mx[r], __shfl_xor(mx[r], 2, 64));
      mx[r] = fmaxf(mx[r], __shfl_xor(mx[r], 4, 64));
      mx[r] = fmaxf(mx[r], __shfl_xor(mx[r], 8, 64));
      nn[r] = fmaxf(mm[r], mx[r]);
      cor[r] = __expf(mm[r] - nn[r]);
      mm[r] = nn[r];
    }
    float pp[4][4];
#pragma unroll
    for (int t = 0; t < 4; t++)
#pragma unroll
      for (int r = 0; r < 4; r++) pp[t][r] = __expf(sc[t][r] - nn[r]);
#pragma unroll
    for (int r = 0; r < 4; r++) {
      sum[r] = (pp[0][r] + pp[1][r]) + (pp[2][r] + pp[3][r]);
      sum[r] += __shfl_xor(sum[r], 1, 64);
      sum[r] += __shfl_xor(sum[r], 2, 64);
      sum[r] += __shfl_xor(sum[r], 4, 64);
      sum[r] += __shfl_xor(sum[r], 8, 64);
      ll[r] = ll[r] * cor[r] + sum[r];
    }
    // ---- P hi into the (dead-Q) QP buffer ----
#pragma unroll
    for (int t = 0; t < 4; t++) {
#pragma unroll
      for (int r = 0; r < 4; r++) {
        accO[t][r] *= cor[r];
        int row = wave * 16 + lg * 4 + r, col = t * 16 + lm;
        QP[SWZ(row, col)] = bfh(pp[t][r]);
      }
    }

    // ---- PV: 1 term (Ph*Vh) ----
    bf16x8 pAh[2];
#pragma unroll
    for (int s = 0; s < 2; s++)
      pAh[s] = *(const bf16x8*)&QP[SWZ(wave * 16 + lm, s * 32 + lg * 8)];
    __builtin_amdgcn_s_setprio(1);
#pragma unroll
    for (int t = 0; t < 4; t++) {
#pragma unroll
      for (int s = 0; s < 2; s++) {
        bf16x8 vb = *(const bf16x8*)&VT[SWZ(t * 16 + lm, s * 32 + lg * 8)];
        accO[t] = __builtin_amdgcn_mfma_f32_16x16x32_bf16(pAh[s], vb, accO[t], 0, 0, 0);
      }
    }
    __builtin_amdgcn_s_setprio(0);
  }
#undef KV_LOAD
#undef KV_WRITE

#pragma unroll
  for (int t = 0; t < 4; t++) {
#pragma unroll
    for (int r = 0; r < 4; r++) {
      int row = q0 + wave * 16 + lg * 4 + r;
      if (row < len)
        atomicAdd(&OH[(size_t)toks[row] * D_ + h * DH_ + t * 16 + lm],
                  accO[t][r] / ll[r]);
    }
  }
}

// ---------------------------------------------------------------------------
extern "C" void kernel_launch(void* const* d_in, const int* in_sizes, int n_in,
                              void* d_out, int out_size, void* d_ws, size_t ws_size,
                              hipStream_t stream) {
  (void)in_sizes; (void)n_in; (void)out_size; (void)ws_size;
  const float* q_in = (const float*)d_in[0];
  const float* k_in = (const float*)d_in[1];
  const float* v_in = (const float*)d_in[2];
  const int* seqlens = (const int*)d_in[3];
  const int* gidx    = (const int*)d_in[4];
  const float* Wq = (const float*)d_in[5];
  const float* Wk = (const float*)d_in[6];
  const float* Wv = (const float*)d_in[7];
  const float* Wo = (const float*)d_in[8];
  float* out = (float*)d_out;

  unsigned short* Qh = (unsigned short*)d_ws;
  unsigned short* Ql = Qh + NELEM_;      // unused
  unsigned short* Kh = Ql + NELEM_;
  unsigned short* Kl = Kh + NELEM_;      // v-split hi staging
  unsigned short* Vh = Kl + NELEM_;
  unsigned short* Vl = Vh + NELEM_;      // q-split hi staging
  float* OH = (float*)(Vl + NELEM_);
  float* WS = OH + NELEM_;               // 2M f32 = 4 x 1M ushort (W his)
  float* FE = WS + (4 << 19);
  float* FQ = FE + (size_t)TTOT_ * DH_;
  float* FK = FQ + (size_t)TTOT_ * DH_;
  float* Wqm = FK + (size_t)TTOT_ * DH_;
  float* Wkm = Wqm + 64 * 1024;
  int* cT = (int*)(Wkm + 64 * 1024);
  int* cL = cT + MAXCL_ * MAXLEN_;
  int* tC = cL + MAXCL_;

  unsigned short* QSh = Vl;                    // q split-hi (Vl slab)
  unsigned short* KSh = (unsigned short*)out;  // k split-hi (d_out, dead until final GEMM)
  unsigned short* VSh = Kl;                    // v split-hi (Kl slab)
  unsigned short* WqH = (unsigned short*)WS;
  unsigned short* WkH = WqH + (1 << 20);
  unsigned short* WvH = WkH + (1 << 20);
  unsigned short* WoH = WvH + (1 << 20);

  // ---- wmean (exact f32, feats dependency) ----
  wmean2<<<dim3(256, 2), 256, 0, stream>>>(Wq, Wk, Wqm, Wkm);

  // ---- feats GEMM (256 blocks) + conversions + tC zeroing ----
  feats_conv<<<256 + (4 * N4W_ + 3 * N4IN_ + NTC4_ + 255) / 256, 256, 0, stream>>>(
      q_in, k_in, v_in, Wqm, Wkm, FQ, FK,
      Wq, Wk, Wv, Wo, WqH, WkH, WvH, WoH, QSh, KSh, VSh, tC);

  l2comb<<<TTOT_ / 4, 256, 0, stream>>>(FQ, FK, FE);

  // ---- routing + Q/K/V GEMMs + OH zeroing fused (32 KB LDS) ----
  fused_qkvr<<<4 + 1536 + 2048, 1024, 0, stream>>>(QSh, WqH, Qh,
                                                   KSh, WkH, Kh,
                                                   VSh, WvH, Vh,
                                                   OH,
                                                   FE, seqlens, gidx, cT, cL, tC);

  // ---- attention (OH already zeroed inside fused_qkvr) ----
  attn_kernel<<<7 * H_ * MAXCL_, 256, 0, stream>>>(
      Qh, Kh, Vh, cT, cL, OH);

  // ---- output GEMM with fused normalize (512 blocks) ----
  gemm_on<<<512, 256, 0, stream>>>(OH, tC, WoH, out);
}